// Round 7
// baseline (1287.392 us; speedup 1.0000x reference)
//
#include <hip/hip_runtime.h>

typedef short short8 __attribute__((ext_vector_type(8)));
typedef float floatx16 __attribute__((ext_vector_type(16)));
typedef float floatx4 __attribute__((ext_vector_type(4)));

#define ROWS 81
#define CDIM 256
#define XSZ  41472      // one x tile: 81 rows x 512 B (bf16, swizzle (r&15)<<4)
#define QT   82944      // q bf16 [81] rows x 256 B, swizzle (r&15)<<4
#define SC   103680     // scores f32 [16][16]
#define AB   104704     // attn bf16 [16][16]
#define TOT  105216

__device__ __forceinline__ unsigned short f2bf(float f) {
    union { float f; unsigned int u; } v; v.f = f;
    return (unsigned short)((v.u + 0x7FFFu + ((v.u >> 16) & 1u)) >> 16);
}

__global__ void wconv_kernel(const float* __restrict__ W,
                             unsigned short* __restrict__ Wb, int n) {
    int i = blockIdx.x * 256 + threadIdx.x;
    if (i < n) Wb[i] = f2bf(W[i]);
}

__device__ __forceinline__ void stage_store(char* xbuf, int k, float4 a0, float4 a1) {
    int gr = k >> 5;
    int c0 = (k & 31) * 8;
    int hh = gr / 9, ww = gr - hh * 9;
    int r = ((hh / 3) * 3 + (ww / 3)) * 9 + ((hh % 3) * 3 + (ww % 3));
    short8 v;
    v[0] = (short)f2bf(a0.x); v[1] = (short)f2bf(a0.y);
    v[2] = (short)f2bf(a0.z); v[3] = (short)f2bf(a0.w);
    v[4] = (short)f2bf(a1.x); v[5] = (short)f2bf(a1.y);
    v[6] = (short)f2bf(a1.z); v[7] = (short)f2bf(a1.w);
    *(short8*)(xbuf + r * 512 + ((c0 * 2) ^ ((r & 15) << 4))) = v;
}

__global__ __launch_bounds__(1024, 4)
void attn_kernel(const float* __restrict__ x,
                 const unsigned short* __restrict__ Wb,
                 const float* __restrict__ b_fc,
                 const int* __restrict__ block_idx,
                 const int* __restrict__ match_vec,
                 float* __restrict__ out,
                 int B, int nIter)
{
    __shared__ __align__(16) char smem[TOT];
    const int t     = threadIdx.x;
    const int lane  = t & 63;
    const int wave  = t >> 6;       // 0..15
    const int l15   = lane & 15;
    const int kg    = lane >> 4;    // 0..3
    const int l31   = lane & 31;
    const int khalf = lane >> 5;    // 0..1
    const int base  = blockIdx.x * nIter;
    if (base >= B) return;

    // consumer waves: W^T B-fragments + bias (L2-hot)
    short8 wfrag[8];
    float bias = 0.f;
    if (wave < 8) {
        const unsigned short* wr = Wb + (wave * 16 + l15) * CDIM + kg * 8;
#pragma unroll
        for (int ks = 0; ks < 8; ++ks)
            wfrag[ks] = *(const short8*)(wr + ks * 32);
        bias = b_fc[wave * 16 + l15];
    }
    const int swl = l15 << 4;

    // ---- prologue: all 16 waves stage batch[base] into X-buffer 0 ----
    {
        const float* xb = x + (size_t)base * (ROWS * CDIM);
        for (int k = t; k < ROWS * 32; k += 1024) {
            float4 a0 = *(const float4*)(xb + k * 8);
            float4 a1 = *(const float4*)(xb + k * 8 + 4);
            stage_store(smem, k, a0, a1);
        }
    }
    __syncthreads();

    for (int it = 0; it < nIter && base + it < B; ++it) {
        const int b = base + it;
        char* xc = smem + (it & 1) * XSZ;          // current batch tile
        char* xn = smem + ((it & 1) ^ 1) * XSZ;    // next batch target
        const bool hasNext = (it + 1 < nIter) && (b + 1 < B);
        const float* xg = x + (size_t)(b + 1) * (ROWS * CDIM);

        if (wave < 8) {
            // ================= CONSUMER: compute batch b =================
            int cm = 0;
            if (wave == 0 && lane < 9) cm = match_vec[block_idx[b]];

            // proj: q[96x128] = x @ W^T, 6 row-tiles x 8 k-steps
            {
                floatx4 acc[6];
#pragma unroll
                for (int ii = 0; ii < 6; ++ii)
#pragma unroll
                    for (int j = 0; j < 4; ++j) acc[ii][j] = 0.f;
#pragma unroll
                for (int ks = 0; ks < 8; ++ks) {
                    int cb = ks * 64 + kg * 16;
#pragma unroll
                    for (int tile = 0; tile < 6; ++tile) {
                        int r = tile * 16 + l15;
                        short8 a = *(const short8*)(xc + r * 512 + (cb ^ swl));
                        acc[tile] = __builtin_amdgcn_mfma_f32_16x16x32_bf16(a, wfrag[ks], acc[tile], 0, 0, 0);
                    }
                }
                int h2 = (wave * 16 + l15) * 2;
#pragma unroll
                for (int tile = 0; tile < 6; ++tile)
#pragma unroll
                    for (int reg = 0; reg < 4; ++reg) {
                        int r = tile * 16 + kg * 4 + reg;
                        if (r < ROWS)
                            *(unsigned short*)(smem + QT + r * 256 + (h2 ^ ((r & 15) << 4))) =
                                f2bf(acc[tile][reg] + bias);
                    }
            }
            __syncthreads();   // B1: q ready

            // fused gram + softmax in wave 0 (same-wave LDS ordering, R5-proven)
            if (wave == 0) {
                floatx4 s0, s1, s2, s3;
#pragma unroll
                for (int ii = 0; ii < 4; ++ii) { s0[ii] = 0.f; s1[ii] = 0.f; s2[ii] = 0.f; s3[ii] = 0.f; }
                int nc = (l15 < 9) ? l15 : 8;
#pragma unroll
                for (int s = 0; s < 9; ++s) {
#pragma unroll
                    for (int ii = 0; ii < 4; ++ii) {
                        int ks = ii * 9 + s;
                        int k  = ks * 32 + kg * 8;
                        int p  = k >> 7;
                        int h0 = (k & 127) * 2;
                        int row = nc * 9 + p;
                        short8 f = *(const short8*)(smem + QT + row * 256 + (h0 ^ ((row & 15) << 4)));
                        floatx4 tmp = __builtin_amdgcn_mfma_f32_16x16x32_bf16(
                            f, f, (ii == 0 ? s0 : ii == 1 ? s1 : ii == 2 ? s2 : s3), 0, 0, 0);
                        if (ii == 0) s0 = tmp; else if (ii == 1) s1 = tmp; else if (ii == 2) s2 = tmp; else s3 = tmp;
                    }
                }
                float* sc = (float*)(smem + SC);
#pragma unroll
                for (int reg = 0; reg < 4; ++reg)
                    sc[(kg * 4 + reg) * 16 + l15] = s0[reg] + s1[reg] + s2[reg] + s3[reg];

                if (lane < 9) {
                    const float scale = 0.029462782549439483f;   // (128*9)^-0.5
                    float s[9];
                    float mx = -1e30f;
#pragma unroll
                    for (int m = 0; m < 9; ++m) {
                        float v = sc[lane * 16 + m] * scale;
                        if (m == lane && cm != 1) v -= 100.f;
                        s[m] = v;
                        mx = fmaxf(mx, v);
                    }
                    float sum = 0.f;
#pragma unroll
                    for (int m = 0; m < 9; ++m) { s[m] = __expf(s[m] - mx); sum += s[m]; }
                    float inv = 1.f / sum;
                    unsigned short* ab = (unsigned short*)(smem + AB) + lane * 16;
#pragma unroll
                    for (int m = 0; m < 9; ++m) ab[m] = f2bf(s[m] * inv);
#pragma unroll
                    for (int m = 9; m < 16; ++m) ab[m] = 0;
                }
            }
            __syncthreads();   // B2: attn ready

            // epilogue: out^T = v^T @ attn^T via 32x32x16; 9 tiles/wave
            {
                const int n  = l31;
                const int nm = (n < 9) ? n : 0;
                short8 bf = *(const short8*)(smem + AB + nm * 32 + khalf * 16);
                float* ob = out + (size_t)b * (ROWS * CDIM);
                int hh = 0, ww = 0;
                if (n < 9) { hh = (n / 3) * 3; ww = (n % 3) * 3; }
#pragma unroll
                for (int tt = 0; tt < 9; ++tt) {
                    int tile = wave * 9 + tt;
                    int d = tile * 32 + l31;
                    int p = d >> 8, c = d & 255;
                    short8 af;
#pragma unroll
                    for (int j = 0; j < 8; ++j) {
                        int mm = khalf * 8 + j; if (mm > 8) mm = 8;   // attn cols >8 are 0
                        int row = mm * 9 + p;
                        af[j] = *(const short*)(xc + row * 512 + ((c * 2) ^ ((row & 15) << 4)));
                    }
                    floatx16 dacc;
#pragma unroll
                    for (int ii = 0; ii < 16; ++ii) dacc[ii] = 0.f;
                    dacc = __builtin_amdgcn_mfma_f32_32x32x16_bf16(af, bf, dacc, 0, 0, 0);
                    if (n < 9) {
#pragma unroll
                        for (int q2 = 0; q2 < 4; ++q2) {
                            int d0 = tile * 32 + q2 * 8 + khalf * 4;
                            int p0 = d0 >> 8, c0 = d0 & 255;
                            int gr = (hh + p0 / 3) * 9 + (ww + p0 % 3);
                            *(float4*)(ob + gr * CDIM + c0) =
                                make_float4(dacc[q2 * 4 + 0], dacc[q2 * 4 + 1],
                                            dacc[q2 * 4 + 2], dacc[q2 * 4 + 3]);
                        }
                    }
                }
            }
            __syncthreads();   // B3: iteration end
        } else {
            // ================= PRODUCER: stage batch b+1 =================
            const int ts = t - 512;   // 0..511
            if (hasNext) {
                // chunk 1: items [0, 1296)  — overlaps proj
                float4 a0[3], a1[3];
                a0[0] = *(const float4*)(xg + ts * 8);
                a1[0] = *(const float4*)(xg + ts * 8 + 4);
                a0[1] = *(const float4*)(xg + (ts + 512) * 8);
                a1[1] = *(const float4*)(xg + (ts + 512) * 8 + 4);
                if (ts < 272) {
                    a0[2] = *(const float4*)(xg + (ts + 1024) * 8);
                    a1[2] = *(const float4*)(xg + (ts + 1024) * 8 + 4);
                }
                stage_store(xn, ts, a0[0], a1[0]);
                stage_store(xn, ts + 512, a0[1], a1[1]);
                if (ts < 272) stage_store(xn, ts + 1024, a0[2], a1[2]);
            }
            __syncthreads();   // B1
            __syncthreads();   // B2
            if (hasNext) {
                // chunk 2: items [1296, 2592) — overlaps epilogue
                float4 a0[3], a1[3];
                a0[0] = *(const float4*)(xg + (ts + 1296) * 8);
                a1[0] = *(const float4*)(xg + (ts + 1296) * 8 + 4);
                a0[1] = *(const float4*)(xg + (ts + 1808) * 8);
                a1[1] = *(const float4*)(xg + (ts + 1808) * 8 + 4);
                if (ts < 272) {
                    a0[2] = *(const float4*)(xg + (ts + 2320) * 8);
                    a1[2] = *(const float4*)(xg + (ts + 2320) * 8 + 4);
                }
                stage_store(xn, ts + 1296, a0[0], a1[0]);
                stage_store(xn, ts + 1808, a0[1], a1[1]);
                if (ts < 272) stage_store(xn, ts + 2320, a0[2], a1[2]);
            }
            __syncthreads();   // B3
        }
    }
}

extern "C" void kernel_launch(void* const* d_in, const int* in_sizes, int n_in,
                              void* d_out, int out_size, void* d_ws, size_t ws_size,
                              hipStream_t stream) {
    const float* x    = (const float*)d_in[0];
    const float* W    = (const float*)d_in[1];
    const float* bfc  = (const float*)d_in[2];
    const int*   bidx = (const int*)d_in[3];
    const int*   mvec = (const int*)d_in[4];
    float* outp = (float*)d_out;
    unsigned short* Wb = (unsigned short*)d_ws;

    int nW = in_sizes[1];                       // 128*256
    wconv_kernel<<<(nW + 255) / 256, 256, 0, stream>>>(W, Wb, nW);

    int B = in_sizes[0] / (ROWS * CDIM);        // 8192
    int grid = (B < 256) ? B : 256;
    int nIter = (B + grid - 1) / grid;          // 32
    attn_kernel<<<grid, 1024, 0, stream>>>(x, Wb, bfc, bidx, mvec, outp, B, nIter);
}

// Round 8
// 365.498 us; speedup vs baseline: 3.5223x; 3.5223x over previous
//
#include <hip/hip_runtime.h>

typedef short short8 __attribute__((ext_vector_type(8)));
typedef float floatx16 __attribute__((ext_vector_type(16)));
typedef float floatx4 __attribute__((ext_vector_type(4)));

#define ROWS 81
#define CDIM 256
// LDS layout: XT bf16 [81][256] p-major rows (r=p*9+m), swizzle SWX, stride 512B
//             QT bf16 [96][128] (padded rows), swizzle (r&15)<<4, stride 256B
//             SC f32 4 partial score tiles [16][16]
//             AB bf16 attn [16][16]
#define XT   0
#define QT   41472
#define SC   66048
#define AB   70144
#define TOT  70656

#define SWX(r) ((((r) & 15) << 4) ^ (((r) & 8) << 3))

__device__ __forceinline__ unsigned short f2bf(float f) {
    union { float f; unsigned int u; } v; v.f = f;
    return (unsigned short)((v.u + 0x7FFFu + ((v.u >> 16) & 1u)) >> 16);
}

__global__ void wconv_kernel(const float* __restrict__ W,
                             unsigned short* __restrict__ Wb, int n) {
    int i = blockIdx.x * 256 + threadIdx.x;
    if (i < n) Wb[i] = f2bf(W[i]);
}

__global__ __launch_bounds__(512, 2)
void attn_kernel(const float* __restrict__ x,
                 const unsigned short* __restrict__ Wb,
                 const float* __restrict__ b_fc,
                 const int* __restrict__ block_idx,
                 const int* __restrict__ match_vec,
                 float* __restrict__ out)
{
    __shared__ __align__(16) char smem[TOT];
    const int b     = blockIdx.x;
    const int t     = threadIdx.x;
    const int lane  = t & 63;
    const int wave  = t >> 6;       // 0..7
    const int l15   = lane & 15;
    const int kg    = lane >> 4;    // 0..3
    const int l31   = lane & 31;
    const int khalf = lane >> 5;    // 0..1

    int cm = 0;
    if (t < 9) cm = match_vec[block_idx[b]];

    // ---- W^T B-fragments (wave's 16 h-cols) + bias (L2-hot) ----
    short8 wfrag[8];
    {
        const unsigned short* wr = Wb + (wave * 16 + l15) * CDIM + kg * 8;
#pragma unroll
        for (int ks = 0; ks < 8; ++ks)
            wfrag[ks] = *(const short8*)(wr + ks * 32);
    }
    const float bias = b_fc[wave * 16 + l15];

    // ---- stage x -> XT bf16, p-major rows, swizzled ----
    {
        const float* xb = x + (size_t)b * (ROWS * CDIM);
        for (int k = t; k < ROWS * 32; k += 512) {
            int gr = k >> 5;
            int c0 = (k & 31) * 8;            // f32 col base
            float4 a0 = *(const float4*)(xb + gr * CDIM + c0);
            float4 a1 = *(const float4*)(xb + gr * CDIM + c0 + 4);
            int hh = gr / 9, ww = gr - hh * 9;
            int p = (hh % 3) * 3 + (ww % 3);
            int m = (hh / 3) * 3 + (ww / 3);
            int r = p * 9 + m;
            short8 v;
            v[0] = (short)f2bf(a0.x); v[1] = (short)f2bf(a0.y);
            v[2] = (short)f2bf(a0.z); v[3] = (short)f2bf(a0.w);
            v[4] = (short)f2bf(a1.x); v[5] = (short)f2bf(a1.y);
            v[6] = (short)f2bf(a1.z); v[7] = (short)f2bf(a1.w);
            *(short8*)(smem + XT + r * 512 + ((c0 * 2) ^ SWX(r))) = v;
        }
    }
    __syncthreads();   // B0: XT ready

    // ---- proj: q[96x128] = x @ W^T via 16x16x32, 6 row-tiles x 8 k-steps ----
    {
        floatx4 acc[6];
#pragma unroll
        for (int ii = 0; ii < 6; ++ii)
#pragma unroll
            for (int j = 0; j < 4; ++j) acc[ii][j] = 0.f;
#pragma unroll
        for (int ks = 0; ks < 8; ++ks) {
            int cb = ks * 64 + kg * 16;       // byte offset of k-chunk
#pragma unroll
            for (int tile = 0; tile < 6; ++tile) {
                int r = tile * 16 + l15;
                short8 a = *(const short8*)(smem + XT + r * 512 + (cb ^ SWX(r)));
                acc[tile] = __builtin_amdgcn_mfma_f32_16x16x32_bf16(a, wfrag[ks], acc[tile], 0, 0, 0);
            }
        }
        int h2 = (wave * 16 + l15) * 2;       // byte col of h
#pragma unroll
        for (int tile = 0; tile < 6; ++tile)
#pragma unroll
            for (int reg = 0; reg < 4; ++reg) {
                int r = tile * 16 + kg * 4 + reg;   // 0..95, QT padded
                *(unsigned short*)(smem + QT + r * 256 + (h2 ^ ((r & 15) << 4))) =
                    f2bf(acc[tile][reg] + bias);
            }
    }
    __syncthreads();   // B1: q ready

    // ---- gram partials: waves 0..3, 9 k-chunks each, no atomics ----
    if (wave < 4) {
        floatx4 g;
#pragma unroll
        for (int ii = 0; ii < 4; ++ii) g[ii] = 0.f;
        int nc = (l15 < 9) ? l15 : 8;
#pragma unroll
        for (int s = 0; s < 9; ++s) {
            int ks = wave + s * 4;            // 0..35
            int kk = ks * 32 + kg * 8;        // bf16 index in [0,1152)
            int p  = kk >> 7;
            int h0 = (kk & 127) * 2;
            int row = p * 9 + nc;
            short8 f = *(const short8*)(smem + QT + row * 256 + (h0 ^ ((row & 15) << 4)));
            g = __builtin_amdgcn_mfma_f32_16x16x32_bf16(f, f, g, 0, 0, 0);
        }
        float* sc = (float*)(smem + SC + wave * 1024);
#pragma unroll
        for (int reg = 0; reg < 4; ++reg)
            sc[(kg * 4 + reg) * 16 + l15] = g[reg];
    }
    __syncthreads();   // B2: partials ready

    // ---- masked softmax rows 0..8 (sum 4 partials); attn bf16 [16][16] ----
    if (t < 9) {
        const float scale = 0.029462782549439483f;   // (128*9)^-0.5
        const float* sc0 = (const float*)(smem + SC);
        const float* sc1 = (const float*)(smem + SC + 1024);
        const float* sc2 = (const float*)(smem + SC + 2048);
        const float* sc3 = (const float*)(smem + SC + 3072);
        float s[9];
        float mx = -1e30f;
#pragma unroll
        for (int m = 0; m < 9; ++m) {
            int o = t * 16 + m;
            float v = (sc0[o] + sc1[o] + sc2[o] + sc3[o]) * scale;
            if (m == t && cm != 1) v -= 100.f;
            s[m] = v;
            mx = fmaxf(mx, v);
        }
        float sum = 0.f;
#pragma unroll
        for (int m = 0; m < 9; ++m) { s[m] = __expf(s[m] - mx); sum += s[m]; }
        float inv = 1.f / sum;
        unsigned short* ab = (unsigned short*)(smem + AB) + t * 16;
#pragma unroll
        for (int m = 0; m < 9; ++m) ab[m] = f2bf(s[m] * inv);
#pragma unroll
        for (int m = 9; m < 16; ++m) ab[m] = 0;
    }
    __syncthreads();   // B3: attn ready

    // ---- out^T = v^T @ attn^T via 32x32x16; 9 d-tiles/wave; zero16 C-in ----
    {
        const int n  = l31;
        const int nm = (n < 9) ? n : 0;
        short8 bf = *(const short8*)(smem + AB + nm * 32 + khalf * 16);
        floatx16 zero16;
#pragma unroll
        for (int ii = 0; ii < 16; ++ii) zero16[ii] = 0.f;
        float* ob = out + (size_t)b * (ROWS * CDIM);
        int hh = 0, ww = 0;
        if (n < 9) { hh = (n / 3) * 3; ww = (n % 3) * 3; }
#pragma unroll
        for (int tt = 0; tt < 9; ++tt) {
            int tile = wave * 9 + tt;
            int p = tile >> 3;                    // pixel (uniform per tile)
            int c = (tile & 7) * 32 + l31;        // f32 col within pixel
            short8 af;
#pragma unroll
            for (int j = 0; j < 8; ++j) {
                int mm = khalf * 8 + j; if (mm > 8) mm = 8;   // attn cols >8 are 0
                int row = p * 9 + mm;                          // consecutive rows
                af[j] = *(const short*)(smem + XT + row * 512 + ((c * 2) ^ SWX(row)));
            }
            floatx16 dacc = __builtin_amdgcn_mfma_f32_32x32x16_bf16(af, bf, zero16, 0, 0, 0);
            if (n < 9) {
#pragma unroll
                for (int q2 = 0; q2 < 4; ++q2) {
                    int c0 = (tile & 7) * 32 + q2 * 8 + khalf * 4;
                    int gr = (hh + p / 3) * 9 + (ww + p % 3);
                    *(float4*)(ob + gr * CDIM + c0) =
                        make_float4(dacc[q2 * 4 + 0], dacc[q2 * 4 + 1],
                                    dacc[q2 * 4 + 2], dacc[q2 * 4 + 3]);
                }
            }
        }
    }
}

extern "C" void kernel_launch(void* const* d_in, const int* in_sizes, int n_in,
                              void* d_out, int out_size, void* d_ws, size_t ws_size,
                              hipStream_t stream) {
    const float* x    = (const float*)d_in[0];
    const float* W    = (const float*)d_in[1];
    const float* bfc  = (const float*)d_in[2];
    const int*   bidx = (const int*)d_in[3];
    const int*   mvec = (const int*)d_in[4];
    float* outp = (float*)d_out;
    unsigned short* Wb = (unsigned short*)d_ws;

    int nW = in_sizes[1];                       // 128*256
    wconv_kernel<<<(nW + 255) / 256, 256, 0, stream>>>(W, Wb, nW);

    int B = in_sizes[0] / (ROWS * CDIM);        // 8192
    attn_kernel<<<B, 512, 0, stream>>>(x, Wb, bfc, bidx, mvec, outp);
}